// Round 1
// baseline (444.118 us; speedup 1.0000x reference)
//
#include <hip/hip_runtime.h>
#include <stdint.h>

#define S_LEN 2048
#define D_DIM 2048
#define NH 32
#define NKV 8
#define HD 64
#define B_SZ 2

typedef unsigned short ushort_t;
typedef __attribute__((ext_vector_type(8))) short short8;
typedef __attribute__((ext_vector_type(4))) float f32x4;

__device__ __forceinline__ float b2f(ushort_t u) {
  union { unsigned int i; float f; } x; x.i = ((unsigned int)u) << 16; return x.f;
}
__device__ __forceinline__ ushort_t f2b(float f) {
  union { float f; unsigned int i; } x; x.f = f;
  unsigned int r = x.i + 0x7FFFu + ((x.i >> 16) & 1u);
  return (ushort_t)(r >> 16);
}

__device__ __forceinline__ void load_lds16(const ushort_t* g, ushort_t* l) {
  __builtin_amdgcn_global_load_lds(
      (const __attribute__((address_space(1))) void*)g,
      (__attribute__((address_space(3))) void*)l, 16, 0, 0);
}

// swizzled LDS access for row-stride-128B tiles: byte ^= (row&7)<<4
__device__ __forceinline__ short8 ld_swz(const ushort_t* base, int row, int colElem) {
  int byte = (row << 7) + (colElem << 1);
  byte ^= (row & 7) << 4;
  return *(const short8*)((const char*)base + byte);
}
__device__ __forceinline__ void st_swz(ushort_t* base, int row, int colElem, ushort_t v) {
  int byte = (row << 7) + (colElem << 1);
  byte ^= (row & 7) << 4;
  *(ushort_t*)((char*)base + byte) = v;
}

// ---------------- fp32 -> bf16 conversion ----------------
__global__ void cvt_bf16(const float* __restrict__ in, ushort_t* __restrict__ out, int n8) {
  int i = blockIdx.x * blockDim.x + threadIdx.x;
  if (i >= n8) return;
  const float4* p = (const float4*)(in + (size_t)i * 8);
  float4 x0 = p[0], x1 = p[1];
  ushort_t u[8] = { f2b(x0.x), f2b(x0.y), f2b(x0.z), f2b(x0.w),
                    f2b(x1.x), f2b(x1.y), f2b(x1.z), f2b(x1.w) };
  *(uint4*)(out + (size_t)i * 8) = *(const uint4*)u;
}

// ---------------- RoPE (interleaved pairs) ----------------
__global__ void rope_kernel(ushort_t* __restrict__ t, const float* __restrict__ cosT,
                            const float* __restrict__ sinT, int heads, int n8) {
  int idx = blockIdx.x * blockDim.x + threadIdx.x;
  if (idx >= n8) return;
  int d8 = idx & 7;                 // 8-elem group within head dim (4 pairs)
  int rest = idx >> 3;              // (b*S+s)*heads + h
  int s = (rest / heads) & (S_LEN - 1);
  float4 c4 = *(const float4*)(cosT + s * 32 + d8 * 4);
  float4 s4 = *(const float4*)(sinT + s * 32 + d8 * 4);
  ushort_t* p = t + (size_t)idx * 8;
  ushort_t u[8]; *(uint4*)u = *(const uint4*)p;
  float c[4] = { c4.x, c4.y, c4.z, c4.w }, sn[4] = { s4.x, s4.y, s4.z, s4.w };
  ushort_t o[8];
#pragma unroll
  for (int j = 0; j < 4; ++j) {
    float re = b2f(u[2 * j]), im = b2f(u[2 * j + 1]);
    o[2 * j]     = f2b(re * c[j] - im * sn[j]);
    o[2 * j + 1] = f2b(re * sn[j] + im * c[j]);
  }
  *(uint4*)p = *(const uint4*)o;
}

// ---------------- V transpose: (B,S,KV,HD) -> (B,KV,HD,S) ----------------
__global__ __launch_bounds__(256) void transpose_v(const ushort_t* __restrict__ v,
                                                   ushort_t* __restrict__ vt) {
  __shared__ ushort_t tile[64][80];   // padded rows (160B, 16B-aligned)
  int st = blockIdx.x, g = blockIdx.y, b = blockIdx.z;
  int tid = threadIdx.x;
#pragma unroll
  for (int p = 0; p < 2; ++p) {
    int o = p * 2048 + tid * 8;
    int s = o >> 6, d = o & 63;
    uint4 val = *(const uint4*)(v + (((size_t)(b * S_LEN + st * 64 + s) * NKV + g) * HD + d));
    *(uint4*)&tile[s][d] = val;
  }
  __syncthreads();
#pragma unroll
  for (int p = 0; p < 2; ++p) {
    int o = p * 2048 + tid * 8;
    int d = o >> 6, s0 = o & 63;
    ushort_t tmp[8];
#pragma unroll
    for (int j = 0; j < 8; ++j) tmp[j] = tile[s0 + j][d];
    *(uint4*)(vt + (((size_t)(b * NKV + g) * HD + d) * S_LEN + st * 64 + s0)) = *(const uint4*)tmp;
  }
}

// ---------------- GEMM: C[m][n] = sum_k A[m][k] * B[n][k]  (m97 structure) ----------------
template <typename OutT>
__global__ __launch_bounds__(256) void gemm_bt(const ushort_t* __restrict__ A,
                                               const ushort_t* __restrict__ Bw,
                                               OutT* __restrict__ C,
                                               int M, int N, int K) {
  __shared__ ushort_t As[128 * 32];
  __shared__ ushort_t Bs[128 * 32];
  const int tid = threadIdx.x;
  const int lane = tid & 63, wave = tid >> 6;
  const int wr = wave >> 1, wc = wave & 1;
  const size_t rb = (size_t)blockIdx.y * 128;
  const size_t cb = (size_t)blockIdx.x * 128;
  f32x4 acc[4][4];
#pragma unroll
  for (int i = 0; i < 4; ++i)
#pragma unroll
    for (int j = 0; j < 4; ++j) acc[i][j] = (f32x4){0.f, 0.f, 0.f, 0.f};

  for (int k0 = 0; k0 < K; k0 += 32) {
    __syncthreads();
#pragma unroll
    for (int c = 0; c < 2; ++c) {
      const int o = c * 4096 + wave * 1024 + lane * 16;   // LDS byte offset
      const int r = o >> 6;                                // 64B per row (32 bf16)
      const int col = (o >> 1) & 31;
      load_lds16(A + (rb + r) * K + k0 + col, As + (c * 4096 + wave * 1024) / 2);
      load_lds16(Bw + (cb + r) * K + k0 + col, Bs + (c * 4096 + wave * 1024) / 2);
    }
    __syncthreads();
    short8 a[4], b[4];
#pragma unroll
    for (int i = 0; i < 4; ++i) {
      a[i] = *(const short8*)(As + (wr * 64 + i * 16 + (lane & 15)) * 32 + (lane >> 4) * 8);
      b[i] = *(const short8*)(Bs + (wc * 64 + i * 16 + (lane & 15)) * 32 + (lane >> 4) * 8);
    }
#pragma unroll
    for (int i = 0; i < 4; ++i)
#pragma unroll
      for (int j = 0; j < 4; ++j)
        acc[i][j] = __builtin_amdgcn_mfma_f32_16x16x32_bf16(a[i], b[j], acc[i][j], 0, 0, 0);
  }
#pragma unroll
  for (int i = 0; i < 4; ++i) {
    const size_t r0 = rb + wr * 64 + i * 16 + ((lane >> 4) * 4);
#pragma unroll
    for (int j = 0; j < 4; ++j) {
      const size_t c0 = cb + wc * 64 + j * 16 + (lane & 15);
#pragma unroll
      for (int r = 0; r < 4; ++r) {
        float v = acc[i][j][r];
        if constexpr (sizeof(OutT) == 2) C[(r0 + r) * N + c0] = f2b(v);
        else                             C[(r0 + r) * N + c0] = v;
      }
    }
  }
}

// ---------------- causal GQA flash attention ----------------
// q: (B*S, H*HD) roped; k: (B*S, KV*HD) roped; vt: (B,KV,HD,S); out: (B*S, H*HD)
__global__ __launch_bounds__(256) void flash_attn(const ushort_t* __restrict__ q,
                                                  const ushort_t* __restrict__ k,
                                                  const ushort_t* __restrict__ vt,
                                                  ushort_t* __restrict__ out) {
  __shared__ ushort_t Ks[64 * 64];     // [kv][hd], swizzled
  __shared__ ushort_t Vs[64 * 64];     // [d][kv],  swizzled (from vt)
  __shared__ ushort_t Ps[4][16 * 64];  // per-wave [q][kv], swizzled
  const int qt = blockIdx.x, h = blockIdx.y, b = blockIdx.z;
  const int g = h >> 2;                // REP = 4
  const int tid = threadIdx.x, lane = tid & 63, wave = tid >> 6;
  const int q0 = qt * 64, qw = q0 + wave * 16;
  const int l15 = lane & 15, lhi = lane >> 4;

  short8 qf[2];
  {
    const ushort_t* qp = q + (size_t)(b * S_LEN + qw + l15) * (NH * HD) + h * HD + lhi * 8;
    qf[0] = *(const short8*)qp;
    qf[1] = *(const short8*)(qp + 32);
  }
  f32x4 oacc[4];
#pragma unroll
  for (int i = 0; i < 4; ++i) oacc[i] = (f32x4){0.f, 0.f, 0.f, 0.f};
  float mrow[4] = { -3e38f, -3e38f, -3e38f, -3e38f };
  float lrow[4] = { 0.f, 0.f, 0.f, 0.f };

  const int nt = qt + 1;
  for (int t = 0; t < nt; ++t) {
    const int kv0 = t * 64;
    __syncthreads();
#pragma unroll
    for (int c = 0; c < 2; ++c) {
      const int o = c * 4096 + wave * 1024 + lane * 16;       // LDS byte offset
      const int r = o >> 7;                                    // 128B rows
      const int col = ((o & 127) ^ ((r & 7) << 4)) >> 1;       // pre-swizzled source
      load_lds16(k + (size_t)(b * S_LEN + kv0 + r) * (NKV * HD) + g * HD + col,
                 Ks + (c * 4096 + wave * 1024) / 2);
      load_lds16(vt + ((size_t)(b * NKV + g) * HD + r) * S_LEN + kv0 + col,
                 Vs + (c * 4096 + wave * 1024) / 2);
    }
    __syncthreads();

    // QK^T: 16q x 64kv per wave
    f32x4 sc[4];
#pragma unroll
    for (int n = 0; n < 4; ++n) {
      const int kvr = n * 16 + l15;
      short8 b0 = ld_swz(Ks, kvr, lhi * 8);
      short8 b1 = ld_swz(Ks, kvr, 32 + lhi * 8);
      f32x4 z = (f32x4){0.f, 0.f, 0.f, 0.f};
      z = __builtin_amdgcn_mfma_f32_16x16x32_bf16(qf[0], b0, z, 0, 0, 0);
      z = __builtin_amdgcn_mfma_f32_16x16x32_bf16(qf[1], b1, z, 0, 0, 0);
      sc[n] = z;
    }
    // scale + causal mask (only diagonal tile needs masking)
    if (kv0 + 63 > qw) {
#pragma unroll
      for (int n = 0; n < 4; ++n) {
        const int kvc = kv0 + n * 16 + l15;
#pragma unroll
        for (int r = 0; r < 4; ++r) {
          const int qr = qw + lhi * 4 + r;
          float vv = sc[n][r] * 0.125f;
          sc[n][r] = (kvc <= qr) ? vv : -1e30f;
        }
      }
    } else {
#pragma unroll
      for (int n = 0; n < 4; ++n)
#pragma unroll
        for (int r = 0; r < 4; ++r) sc[n][r] *= 0.125f;
    }
    // online softmax (rows live in 16-lane groups)
    float pmax[4];
#pragma unroll
    for (int r = 0; r < 4; ++r) {
      float m = fmaxf(fmaxf(sc[0][r], sc[1][r]), fmaxf(sc[2][r], sc[3][r]));
      m = fmaxf(m, __shfl_xor(m, 1));
      m = fmaxf(m, __shfl_xor(m, 2));
      m = fmaxf(m, __shfl_xor(m, 4));
      m = fmaxf(m, __shfl_xor(m, 8));
      pmax[r] = m;
    }
    float sold[4], rsum[4];
#pragma unroll
    for (int r = 0; r < 4; ++r) {
      float mnew = fmaxf(mrow[r], pmax[r]);
      sold[r] = __expf(mrow[r] - mnew);
      mrow[r] = mnew;
      rsum[r] = 0.f;
    }
#pragma unroll
    for (int n = 0; n < 4; ++n)
#pragma unroll
      for (int r = 0; r < 4; ++r) {
        float p = __expf(sc[n][r] - mrow[r]);
        rsum[r] += p;
        st_swz(Ps[wave], lhi * 4 + r, n * 16 + l15, f2b(p));
      }
#pragma unroll
    for (int r = 0; r < 4; ++r) {
      float s = rsum[r];
      s += __shfl_xor(s, 1); s += __shfl_xor(s, 2);
      s += __shfl_xor(s, 4); s += __shfl_xor(s, 8);
      lrow[r] = lrow[r] * sold[r] + s;
    }
#pragma unroll
    for (int i = 0; i < 4; ++i) {
      f32x4 t4 = oacc[i];
      t4[0] *= sold[0]; t4[1] *= sold[1]; t4[2] *= sold[2]; t4[3] *= sold[3];
      oacc[i] = t4;
    }
    // PV: out(16q x 64d) += P(16q x 64kv) @ V(64kv x 64d)
    short8 a0 = ld_swz(Ps[wave], l15, lhi * 8);
    short8 a1 = ld_swz(Ps[wave], l15, 32 + lhi * 8);
#pragma unroll
    for (int nd = 0; nd < 4; ++nd) {
      short8 vb0 = ld_swz(Vs, nd * 16 + l15, lhi * 8);
      short8 vb1 = ld_swz(Vs, nd * 16 + l15, 32 + lhi * 8);
      oacc[nd] = __builtin_amdgcn_mfma_f32_16x16x32_bf16(a0, vb0, oacc[nd], 0, 0, 0);
      oacc[nd] = __builtin_amdgcn_mfma_f32_16x16x32_bf16(a1, vb1, oacc[nd], 0, 0, 0);
    }
  }
  // epilogue: normalize and store bf16
#pragma unroll
  for (int nd = 0; nd < 4; ++nd)
#pragma unroll
    for (int r = 0; r < 4; ++r) {
      const size_t row = (size_t)(b * S_LEN + qw + lhi * 4 + r);
      out[row * (NH * HD) + h * HD + nd * 16 + l15] = f2b(oacc[nd][r] / lrow[r]);
    }
}

extern "C" void kernel_launch(void* const* d_in, const int* in_sizes, int n_in,
                              void* d_out, int out_size, void* d_ws, size_t ws_size,
                              hipStream_t stream) {
  const float* x  = (const float*)d_in[0];
  const float* fc = (const float*)d_in[1];
  const float* fs = (const float*)d_in[2];
  const float* wq = (const float*)d_in[3];
  const float* wk = (const float*)d_in[4];
  const float* wv = (const float*)d_in[5];
  const float* wo = (const float*)d_in[6];
  float* out = (float*)d_out;
  ushort_t* ws = (ushort_t*)d_ws;

  const size_t n_x  = (size_t)B_SZ * S_LEN * D_DIM;   // 8388608
  const size_t n_wq = (size_t)NH * HD * D_DIM;        // 4194304
  const size_t n_wk = (size_t)NKV * HD * D_DIM;       // 1048576
  const size_t n_q  = (size_t)B_SZ * S_LEN * NH * HD; // 8388608
  const size_t n_k  = (size_t)B_SZ * S_LEN * NKV * HD;// 2097152

  size_t off = 0;
  ushort_t* xb  = ws + off; off += n_x;
  ushort_t* wqb = ws + off; off += n_wq;
  ushort_t* wkb = ws + off; off += n_wk;
  ushort_t* wvb = ws + off; off += n_wk;
  ushort_t* wob = ws + off; off += n_wq;
  ushort_t* qb  = ws + off; off += n_q;
  ushort_t* kb  = ws + off; off += n_k;
  ushort_t* vb  = ws + off; off += n_k;
  ushort_t* vtb = ws + off; off += n_k;
  ushort_t* ab  = ws + off; off += n_q;
  (void)ws_size; (void)in_sizes; (void)n_in; (void)out_size;

  auto cvt = [&](const float* src, ushort_t* dst, size_t n) {
    int n8 = (int)(n / 8);
    cvt_bf16<<<dim3((n8 + 255) / 256), dim3(256), 0, stream>>>(src, dst, n8);
  };
  cvt(x, xb, n_x);
  cvt(wq, wqb, n_wq);
  cvt(wk, wkb, n_wk);
  cvt(wv, wvb, n_wk);
  cvt(wo, wob, n_wq);

  const int M = B_SZ * S_LEN;  // 4096
  gemm_bt<ushort_t><<<dim3(D_DIM / 128, M / 128), 256, 0, stream>>>(xb, wqb, qb, M, NH * HD, D_DIM);
  gemm_bt<ushort_t><<<dim3((NKV * HD) / 128, M / 128), 256, 0, stream>>>(xb, wkb, kb, M, NKV * HD, D_DIM);
  gemm_bt<ushort_t><<<dim3((NKV * HD) / 128, M / 128), 256, 0, stream>>>(xb, wvb, vb, M, NKV * HD, D_DIM);

  rope_kernel<<<dim3((B_SZ * S_LEN * NH * 8) / 256), 256, 0, stream>>>(qb, fc, fs, NH, B_SZ * S_LEN * NH * 8);
  rope_kernel<<<dim3((B_SZ * S_LEN * NKV * 8) / 256), 256, 0, stream>>>(kb, fc, fs, NKV, B_SZ * S_LEN * NKV * 8);

  transpose_v<<<dim3(S_LEN / 64, NKV, B_SZ), 256, 0, stream>>>(vb, vtb);

  flash_attn<<<dim3(S_LEN / 64, NH, B_SZ), 256, 0, stream>>>(qb, kb, vtb, ab);

  gemm_bt<float><<<dim3(D_DIM / 128, M / 128), 256, 0, stream>>>(ab, wob, out, M, D_DIM, D_DIM);
}

// Round 2
// 297.154 us; speedup vs baseline: 1.4946x; 1.4946x over previous
//
#include <hip/hip_runtime.h>
#include <stdint.h>

#define S_LEN 2048
#define D_DIM 2048
#define NH 32
#define NKV 8
#define HD 64
#define B_SZ 2
#define QKV_N 3072          // fused projection output width: 2048 q | 512 k | 512 v
#define K_OFF 2048
#define V_OFF 2560
#define SCL 0.1803368801111244f   /* (1/sqrt(64)) * log2(e) */

typedef unsigned short ushort_t;
typedef __attribute__((ext_vector_type(8))) short short8;
typedef __attribute__((ext_vector_type(4))) float f32x4;

__device__ __forceinline__ float b2f(ushort_t u) {
  union { unsigned int i; float f; } x; x.i = ((unsigned int)u) << 16; return x.f;
}
__device__ __forceinline__ ushort_t f2b(float f) {
  union { float f; unsigned int i; } x; x.f = f;
  unsigned int r = x.i + 0x7FFFu + ((x.i >> 16) & 1u);
  return (ushort_t)(r >> 16);
}

__device__ __forceinline__ void load_lds16(const ushort_t* g, ushort_t* l) {
  __builtin_amdgcn_global_load_lds(
      (const __attribute__((address_space(1))) void*)g,
      (__attribute__((address_space(3))) void*)l, 16, 0, 0);
}

// swizzled LDS access for row-stride-128B tiles: byte ^= (row&7)<<4
__device__ __forceinline__ short8 ld_swz(const ushort_t* base, int row, int colElem) {
  int byte = (row << 7) + (colElem << 1);
  byte ^= (row & 7) << 4;
  return *(const short8*)((const char*)base + byte);
}
__device__ __forceinline__ void st_swz(ushort_t* base, int row, int colElem, ushort_t v) {
  int byte = (row << 7) + (colElem << 1);
  byte ^= (row & 7) << 4;
  *(ushort_t*)((char*)base + byte) = v;
}

// ---------------- fp32 -> bf16 conversion ----------------
__global__ void cvt_bf16(const float* __restrict__ in, ushort_t* __restrict__ out, int n8) {
  int i = blockIdx.x * blockDim.x + threadIdx.x;
  if (i >= n8) return;
  const float4* p = (const float4*)(in + (size_t)i * 8);
  float4 x0 = p[0], x1 = p[1];
  ushort_t u[8] = { f2b(x0.x), f2b(x0.y), f2b(x0.z), f2b(x0.w),
                    f2b(x1.x), f2b(x1.y), f2b(x1.z), f2b(x1.w) };
  *(uint4*)(out + (size_t)i * 8) = *(const uint4*)u;
}

// ---------------- RoPE (interleaved pairs), strided rows ----------------
template <int HEADS, int LOG2H>
__global__ void rope_kernel(ushort_t* __restrict__ t, const float* __restrict__ cosT,
                            const float* __restrict__ sinT, int n8) {
  int idx = blockIdx.x * blockDim.x + threadIdx.x;
  if (idx >= n8) return;
  int d8 = idx & 7;                       // 8-elem group within head dim
  int rest = idx >> 3;
  int h = rest & (HEADS - 1);
  int row = rest >> LOG2H;                // b*S + s
  int s = row & (S_LEN - 1);
  float4 c4 = *(const float4*)(cosT + s * 32 + d8 * 4);
  float4 s4 = *(const float4*)(sinT + s * 32 + d8 * 4);
  ushort_t* p = t + (size_t)row * QKV_N + h * HD + d8 * 8;
  ushort_t u[8]; *(uint4*)u = *(const uint4*)p;
  float c[4] = { c4.x, c4.y, c4.z, c4.w }, sn[4] = { s4.x, s4.y, s4.z, s4.w };
  ushort_t o[8];
#pragma unroll
  for (int j = 0; j < 4; ++j) {
    float re = b2f(u[2 * j]), im = b2f(u[2 * j + 1]);
    o[2 * j]     = f2b(re * c[j] - im * sn[j]);
    o[2 * j + 1] = f2b(re * sn[j] + im * c[j]);
  }
  *(uint4*)p = *(const uint4*)o;
}

// ---------------- V transpose: strided (B,S,KV,HD) slice -> (B,KV,HD,S) ----------------
__global__ __launch_bounds__(256) void transpose_v(const ushort_t* __restrict__ v,
                                                   ushort_t* __restrict__ vt) {
  __shared__ ushort_t tile[64][80];
  int st = blockIdx.x, g = blockIdx.y, b = blockIdx.z;
  int tid = threadIdx.x;
#pragma unroll
  for (int p = 0; p < 2; ++p) {
    int o = p * 2048 + tid * 8;
    int s = o >> 6, d = o & 63;
    uint4 val = *(const uint4*)(v + ((size_t)(b * S_LEN + st * 64 + s) * QKV_N + g * HD + d));
    *(uint4*)&tile[s][d] = val;
  }
  __syncthreads();
#pragma unroll
  for (int p = 0; p < 2; ++p) {
    int o = p * 2048 + tid * 8;
    int d = o >> 6, s0 = o & 63;
    ushort_t tmp[8];
#pragma unroll
    for (int j = 0; j < 8; ++j) tmp[j] = tile[s0 + j][d];
    *(uint4*)(vt + (((size_t)(b * NKV + g) * HD + d) * S_LEN + st * 64 + s0)) = *(const uint4*)tmp;
  }
}

// ---------------- GEMM: C[m][n] = sum_k A[m][k] * B[n][k]  (m97 structure) ----------------
template <typename OutT>
__global__ __launch_bounds__(256) void gemm_bt(const ushort_t* __restrict__ A,
                                               const ushort_t* __restrict__ Bw,
                                               OutT* __restrict__ C,
                                               int M, int N, int K) {
  __shared__ ushort_t As[128 * 32];
  __shared__ ushort_t Bs[128 * 32];
  const int tid = threadIdx.x;
  const int lane = tid & 63, wave = tid >> 6;
  const int wr = wave >> 1, wc = wave & 1;
  const size_t rb = (size_t)blockIdx.y * 128;
  const size_t cb = (size_t)blockIdx.x * 128;
  f32x4 acc[4][4];
#pragma unroll
  for (int i = 0; i < 4; ++i)
#pragma unroll
    for (int j = 0; j < 4; ++j) acc[i][j] = (f32x4){0.f, 0.f, 0.f, 0.f};

  for (int k0 = 0; k0 < K; k0 += 32) {
    __syncthreads();
#pragma unroll
    for (int c = 0; c < 2; ++c) {
      const int o = c * 4096 + wave * 1024 + lane * 16;
      const int r = o >> 6;
      const int col = (o >> 1) & 31;
      load_lds16(A + (rb + r) * K + k0 + col, As + (c * 4096 + wave * 1024) / 2);
      load_lds16(Bw + (cb + r) * K + k0 + col, Bs + (c * 4096 + wave * 1024) / 2);
    }
    __syncthreads();
    short8 a[4], b[4];
#pragma unroll
    for (int i = 0; i < 4; ++i) {
      a[i] = *(const short8*)(As + (wr * 64 + i * 16 + (lane & 15)) * 32 + (lane >> 4) * 8);
      b[i] = *(const short8*)(Bs + (wc * 64 + i * 16 + (lane & 15)) * 32 + (lane >> 4) * 8);
    }
#pragma unroll
    for (int i = 0; i < 4; ++i)
#pragma unroll
      for (int j = 0; j < 4; ++j)
        acc[i][j] = __builtin_amdgcn_mfma_f32_16x16x32_bf16(a[i], b[j], acc[i][j], 0, 0, 0);
  }
#pragma unroll
  for (int i = 0; i < 4; ++i) {
    const size_t r0 = rb + wr * 64 + i * 16 + ((lane >> 4) * 4);
#pragma unroll
    for (int j = 0; j < 4; ++j) {
      const size_t c0 = cb + wc * 64 + j * 16 + (lane & 15);
#pragma unroll
      for (int r = 0; r < 4; ++r) {
        float v = acc[i][j][r];
        if constexpr (sizeof(OutT) == 2) C[(r0 + r) * N + c0] = f2b(v);
        else                             C[(r0 + r) * N + c0] = v;
      }
    }
  }
}

// ---------------- causal GQA flash attention ----------------
// q: strided (B*S, QKV_N) base at q-cols; k: base at k-cols; vt: (B,KV,HD,S); out: (B*S, H*HD)
// Block: 4 waves x 16 q-rows = 64 q-rows; processes q-tile pair (i, 31-i) for balance.
// K/V double-buffered in LDS, one barrier per KV tile (stage of t+1 overlaps compute of t).
__global__ __launch_bounds__(256) void flash_attn(const ushort_t* __restrict__ q,
                                                  const ushort_t* __restrict__ k,
                                                  const ushort_t* __restrict__ vt,
                                                  ushort_t* __restrict__ out) {
  __shared__ ushort_t Ks[2][64 * 64];
  __shared__ ushort_t Vs[2][64 * 64];
  __shared__ ushort_t Ps[4][16 * 64];
  const int pairIdx = blockIdx.x, h = blockIdx.y, b = blockIdx.z;
  const int g = h >> 2;                 // REP = 4
  const int tid = threadIdx.x, lane = tid & 63, wave = tid >> 6;
  const int l15 = lane & 15, lhi = lane >> 4;

  // per-thread staging geometry (16B per load, 2 passes each for K and V)
  int srcRow[2], srcColK[2], srcColV[2], ldsOff[2];
#pragma unroll
  for (int c = 0; c < 2; ++c) {
    const int o = c * 4096 + wave * 1024 + lane * 16;      // byte offset in 8KB buffer
    const int r = o >> 7;                                   // 128B rows
    const int col = ((o & 127) ^ ((r & 7) << 4)) >> 1;      // pre-swizzled source col
    srcRow[c] = r; srcColK[c] = col; srcColV[c] = col;
    ldsOff[c] = (c * 4096 + wave * 1024) / 2;
  }
  const ushort_t* kbase = k + (size_t)b * S_LEN * QKV_N + g * HD;
  const ushort_t* vbase = vt + (size_t)(b * NKV + g) * HD * S_LEN;

#pragma unroll 1
  for (int half = 0; half < 2; ++half) {
    const int qt = (half == 0) ? pairIdx : (31 - pairIdx);
    const int qw = qt * 64 + wave * 16;

    short8 qf[2];
    {
      const ushort_t* qp = q + (size_t)(b * S_LEN + qw + l15) * QKV_N + h * HD + lhi * 8;
      qf[0] = *(const short8*)qp;
      qf[1] = *(const short8*)(qp + 32);
    }
    f32x4 oacc[4];
#pragma unroll
    for (int i = 0; i < 4; ++i) oacc[i] = (f32x4){0.f, 0.f, 0.f, 0.f};
    float mrow[4] = { -3e38f, -3e38f, -3e38f, -3e38f };
    float lrow[4] = { 0.f, 0.f, 0.f, 0.f };

    // prologue stage tile 0 into buf 0
#pragma unroll
    for (int c = 0; c < 2; ++c) {
      load_lds16(kbase + (size_t)srcRow[c] * QKV_N + srcColK[c], &Ks[0][ldsOff[c]]);
      load_lds16(vbase + (size_t)srcRow[c] * S_LEN + srcColV[c], &Vs[0][ldsOff[c]]);
    }
    __syncthreads();

    int cur = 0;
    const int nt = qt + 1;
    for (int t = 0; t < nt; ++t) {
      const int kv0 = t * 64;
      // stage next tile into the other buffer (overlaps with compute below)
      if (t + 1 < nt) {
        const int nk = kv0 + 64;
#pragma unroll
        for (int c = 0; c < 2; ++c) {
          load_lds16(kbase + (size_t)(nk + srcRow[c]) * QKV_N + srcColK[c], &Ks[cur ^ 1][ldsOff[c]]);
          load_lds16(vbase + (size_t)srcRow[c] * S_LEN + nk + srcColV[c], &Vs[cur ^ 1][ldsOff[c]]);
        }
      }

      // QK^T: 16q x 64kv per wave
      f32x4 sc[4];
#pragma unroll
      for (int n = 0; n < 4; ++n) {
        const int kvr = n * 16 + l15;
        short8 b0 = ld_swz(Ks[cur], kvr, lhi * 8);
        short8 b1 = ld_swz(Ks[cur], kvr, 32 + lhi * 8);
        f32x4 z = (f32x4){0.f, 0.f, 0.f, 0.f};
        z = __builtin_amdgcn_mfma_f32_16x16x32_bf16(qf[0], b0, z, 0, 0, 0);
        z = __builtin_amdgcn_mfma_f32_16x16x32_bf16(qf[1], b1, z, 0, 0, 0);
        sc[n] = z;
      }
      // scale into log2 domain + causal mask (only diagonal tile)
      if (t == qt) {
#pragma unroll
        for (int n = 0; n < 4; ++n) {
          const int kvc = kv0 + n * 16 + l15;
#pragma unroll
          for (int r = 0; r < 4; ++r) {
            const int qr = qw + lhi * 4 + r;
            float vv = sc[n][r] * SCL;
            sc[n][r] = (kvc <= qr) ? vv : -1e30f;
          }
        }
      } else {
#pragma unroll
        for (int n = 0; n < 4; ++n)
#pragma unroll
          for (int r = 0; r < 4; ++r) sc[n][r] *= SCL;
      }
      // online softmax in exp2 domain (rows live in 16-lane groups)
      float pmax[4];
#pragma unroll
      for (int r = 0; r < 4; ++r) {
        float m = fmaxf(fmaxf(sc[0][r], sc[1][r]), fmaxf(sc[2][r], sc[3][r]));
        m = fmaxf(m, __shfl_xor(m, 1));
        m = fmaxf(m, __shfl_xor(m, 2));
        m = fmaxf(m, __shfl_xor(m, 4));
        m = fmaxf(m, __shfl_xor(m, 8));
        pmax[r] = m;
      }
      float sold[4], rsum[4];
#pragma unroll
      for (int r = 0; r < 4; ++r) {
        float mnew = fmaxf(mrow[r], pmax[r]);
        sold[r] = exp2f(mrow[r] - mnew);
        mrow[r] = mnew;
        rsum[r] = 0.f;
      }
#pragma unroll
      for (int n = 0; n < 4; ++n)
#pragma unroll
        for (int r = 0; r < 4; ++r) {
          float p = exp2f(sc[n][r] - mrow[r]);
          rsum[r] += p;
          st_swz(Ps[wave], lhi * 4 + r, n * 16 + l15, f2b(p));
        }
#pragma unroll
      for (int r = 0; r < 4; ++r) {
        float s = rsum[r];
        s += __shfl_xor(s, 1); s += __shfl_xor(s, 2);
        s += __shfl_xor(s, 4); s += __shfl_xor(s, 8);
        lrow[r] = lrow[r] * sold[r] + s;
      }
#pragma unroll
      for (int i = 0; i < 4; ++i) {
        f32x4 t4 = oacc[i];
        t4[0] *= sold[0]; t4[1] *= sold[1]; t4[2] *= sold[2]; t4[3] *= sold[3];
        oacc[i] = t4;
      }
      // PV: out(16q x 64d) += P(16q x 64kv) @ Vt(64d x 64kv)^T
      short8 a0 = ld_swz(Ps[wave], l15, lhi * 8);
      short8 a1 = ld_swz(Ps[wave], l15, 32 + lhi * 8);
#pragma unroll
      for (int nd = 0; nd < 4; ++nd) {
        short8 vb0 = ld_swz(Vs[cur], nd * 16 + l15, lhi * 8);
        short8 vb1 = ld_swz(Vs[cur], nd * 16 + l15, 32 + lhi * 8);
        oacc[nd] = __builtin_amdgcn_mfma_f32_16x16x32_bf16(a0, vb0, oacc[nd], 0, 0, 0);
        oacc[nd] = __builtin_amdgcn_mfma_f32_16x16x32_bf16(a1, vb1, oacc[nd], 0, 0, 0);
      }
      __syncthreads();      // drains staged loads; next tile ready
      cur ^= 1;
    }
    // epilogue: normalize and store bf16
#pragma unroll
    for (int nd = 0; nd < 4; ++nd)
#pragma unroll
      for (int r = 0; r < 4; ++r) {
        const size_t row = (size_t)(b * S_LEN + qw + lhi * 4 + r);
        out[row * (NH * HD) + h * HD + nd * 16 + l15] = f2b(oacc[nd][r] / lrow[r]);
      }
  }
}

extern "C" void kernel_launch(void* const* d_in, const int* in_sizes, int n_in,
                              void* d_out, int out_size, void* d_ws, size_t ws_size,
                              hipStream_t stream) {
  const float* x  = (const float*)d_in[0];
  const float* fc = (const float*)d_in[1];
  const float* fs = (const float*)d_in[2];
  const float* wq = (const float*)d_in[3];
  const float* wk = (const float*)d_in[4];
  const float* wv = (const float*)d_in[5];
  const float* wo = (const float*)d_in[6];
  float* out = (float*)d_out;
  ushort_t* ws = (ushort_t*)d_ws;

  const size_t n_x   = (size_t)B_SZ * S_LEN * D_DIM;    // 8388608
  const size_t n_wq  = (size_t)NH * HD * D_DIM;         // 4194304
  const size_t n_wk  = (size_t)NKV * HD * D_DIM;        // 1048576
  const size_t n_qkv = (size_t)B_SZ * S_LEN * QKV_N;    // 12582912
  const size_t n_q   = (size_t)B_SZ * S_LEN * NH * HD;  // 8388608
  const size_t n_k   = (size_t)B_SZ * S_LEN * NKV * HD; // 2097152

  size_t off = 0;
  ushort_t* xb   = ws + off; off += n_x;
  ushort_t* wqb  = ws + off; off += n_wq;   // wq | wk | wv contiguous = (3072, 2048)
  ushort_t* wkb  = ws + off; off += n_wk;
  ushort_t* wvb  = ws + off; off += n_wk;
  ushort_t* wob  = ws + off; off += n_wq;
  ushort_t* qkvb = ws + off; off += n_qkv;  // (4096, 3072): q | k | v
  ushort_t* vtb  = ws + off; off += n_k;
  ushort_t* ab   = ws + off; off += n_q;
  (void)ws_size; (void)in_sizes; (void)n_in; (void)out_size;

  auto cvt = [&](const float* src, ushort_t* dst, size_t n) {
    int n8 = (int)(n / 8);
    cvt_bf16<<<dim3((n8 + 255) / 256), dim3(256), 0, stream>>>(src, dst, n8);
  };
  cvt(x, xb, n_x);
  cvt(wq, wqb, n_wq);
  cvt(wk, wkb, n_wk);
  cvt(wv, wvb, n_wk);
  cvt(wo, wob, n_wq);

  const int M = B_SZ * S_LEN;  // 4096
  // fused Q/K/V projection: (4096, 2048) @ (3072, 2048)^T -> (4096, 3072)
  gemm_bt<ushort_t><<<dim3(QKV_N / 128, M / 128), 256, 0, stream>>>(xb, wqb, qkvb, M, QKV_N, D_DIM);

  rope_kernel<NH, 5><<<dim3((M * NH * 8) / 256), 256, 0, stream>>>(qkvb, fc, fs, M * NH * 8);
  rope_kernel<NKV, 3><<<dim3((M * NKV * 8) / 256), 256, 0, stream>>>(qkvb + K_OFF, fc, fs, M * NKV * 8);

  transpose_v<<<dim3(S_LEN / 64, NKV, B_SZ), 256, 0, stream>>>(qkvb + V_OFF, vtb);

  flash_attn<<<dim3(16, NH, B_SZ), 256, 0, stream>>>(qkvb, qkvb + K_OFF, vtb, ab);

  gemm_bt<float><<<dim3(D_DIM / 128, M / 128), 256, 0, stream>>>(ab, wob, out, M, D_DIM, D_DIM);
}

// Round 3
// 244.291 us; speedup vs baseline: 1.8180x; 1.2164x over previous
//
#include <hip/hip_runtime.h>
#include <stdint.h>

#define S_LEN 2048
#define D_DIM 2048
#define NH 32
#define NKV 8
#define HD 64
#define B_SZ 2
#define QKV_N 3072          // fused projection output width: 2048 q | 512 k | 512 v
#define K_OFF 2048
#define V_OFF 2560
#define SCL 0.1803368801111244f   /* (1/sqrt(64)) * log2(e) */

typedef unsigned short ushort_t;
typedef __attribute__((ext_vector_type(8))) short short8;
typedef __attribute__((ext_vector_type(4))) float f32x4;
typedef __attribute__((ext_vector_type(16))) float f32x16;

__device__ __forceinline__ float b2f(ushort_t u) {
  union { unsigned int i; float f; } x; x.i = ((unsigned int)u) << 16; return x.f;
}
__device__ __forceinline__ ushort_t f2b(float f) {
  union { float f; unsigned int i; } x; x.f = f;
  unsigned int r = x.i + 0x7FFFu + ((x.i >> 16) & 1u);
  return (ushort_t)(r >> 16);
}

__device__ __forceinline__ void load_lds16(const ushort_t* g, ushort_t* l) {
  __builtin_amdgcn_global_load_lds(
      (const __attribute__((address_space(1))) void*)g,
      (__attribute__((address_space(3))) void*)l, 16, 0, 0);
}

// swizzled LDS access for row-stride-128B tiles: byte ^= (row&7)<<4
__device__ __forceinline__ short8 ld_swz(const ushort_t* base, int row, int colElem) {
  int byte = (row << 7) + (colElem << 1);
  byte ^= (row & 7) << 4;
  return *(const short8*)((const char*)base + byte);
}

// pack two f32 -> one u32 of 2 bf16 (src0 -> low half)
__device__ __forceinline__ uint32_t cvtpk(float a, float b) {
  uint32_t r;
  asm("v_cvt_pk_bf16_f32 %0, %1, %2" : "=v"(r) : "v"(a), "v"(b));
  return r;
}
// exchange a[lanes 32-63] with b[lanes 0-31]
__device__ __forceinline__ void pswap(uint32_t& a, uint32_t& b) {
  asm("v_permlane32_swap_b32 %0, %1" : "+v"(a), "+v"(b));
}
__device__ __forceinline__ short8 mk8(uint32_t w0, uint32_t w1, uint32_t w2, uint32_t w3) {
  union { uint32_t w[4]; short8 v; } u;
  u.w[0] = w0; u.w[1] = w1; u.w[2] = w2; u.w[3] = w3;
  return u.v;
}

// ---------------- fp32 -> bf16 conversion ----------------
__global__ void cvt_bf16(const float* __restrict__ in, ushort_t* __restrict__ out, int n8) {
  int i = blockIdx.x * blockDim.x + threadIdx.x;
  if (i >= n8) return;
  const float4* p = (const float4*)(in + (size_t)i * 8);
  float4 x0 = p[0], x1 = p[1];
  ushort_t u[8] = { f2b(x0.x), f2b(x0.y), f2b(x0.z), f2b(x0.w),
                    f2b(x1.x), f2b(x1.y), f2b(x1.z), f2b(x1.w) };
  *(uint4*)(out + (size_t)i * 8) = *(const uint4*)u;
}

// ---------------- RoPE (interleaved pairs), strided rows ----------------
template <int HEADS, int LOG2H>
__global__ void rope_kernel(ushort_t* __restrict__ t, const float* __restrict__ cosT,
                            const float* __restrict__ sinT, int n8) {
  int idx = blockIdx.x * blockDim.x + threadIdx.x;
  if (idx >= n8) return;
  int d8 = idx & 7;
  int rest = idx >> 3;
  int h = rest & (HEADS - 1);
  int row = rest >> LOG2H;                // b*S + s
  int s = row & (S_LEN - 1);
  float4 c4 = *(const float4*)(cosT + s * 32 + d8 * 4);
  float4 s4 = *(const float4*)(sinT + s * 32 + d8 * 4);
  ushort_t* p = t + (size_t)row * QKV_N + h * HD + d8 * 8;
  ushort_t u[8]; *(uint4*)u = *(const uint4*)p;
  float c[4] = { c4.x, c4.y, c4.z, c4.w }, sn[4] = { s4.x, s4.y, s4.z, s4.w };
  ushort_t o[8];
#pragma unroll
  for (int j = 0; j < 4; ++j) {
    float re = b2f(u[2 * j]), im = b2f(u[2 * j + 1]);
    o[2 * j]     = f2b(re * c[j] - im * sn[j]);
    o[2 * j + 1] = f2b(re * sn[j] + im * c[j]);
  }
  *(uint4*)p = *(const uint4*)o;
}

// ---------------- V transpose: strided (B,S,KV,HD) slice -> (B,KV,HD,S) ----------------
__global__ __launch_bounds__(256) void transpose_v(const ushort_t* __restrict__ v,
                                                   ushort_t* __restrict__ vt) {
  __shared__ ushort_t tile[64][80];
  int st = blockIdx.x, g = blockIdx.y, b = blockIdx.z;
  int tid = threadIdx.x;
#pragma unroll
  for (int p = 0; p < 2; ++p) {
    int o = p * 2048 + tid * 8;
    int s = o >> 6, d = o & 63;
    uint4 val = *(const uint4*)(v + ((size_t)(b * S_LEN + st * 64 + s) * QKV_N + g * HD + d));
    *(uint4*)&tile[s][d] = val;
  }
  __syncthreads();
#pragma unroll
  for (int p = 0; p < 2; ++p) {
    int o = p * 2048 + tid * 8;
    int d = o >> 6, s0 = o & 63;
    ushort_t tmp[8];
#pragma unroll
    for (int j = 0; j < 8; ++j) tmp[j] = tile[s0 + j][d];
    *(uint4*)(vt + (((size_t)(b * NKV + g) * HD + d) * S_LEN + st * 64 + s0)) = *(const uint4*)tmp;
  }
}

// ---------------- GEMM: C[m][n] = sum_k A[m][k] * B[n][k]  (m97 structure) ----------------
template <typename OutT>
__global__ __launch_bounds__(256) void gemm_bt(const ushort_t* __restrict__ A,
                                               const ushort_t* __restrict__ Bw,
                                               OutT* __restrict__ C,
                                               int M, int N, int K) {
  __shared__ ushort_t As[128 * 32];
  __shared__ ushort_t Bs[128 * 32];
  const int tid = threadIdx.x;
  const int lane = tid & 63, wave = tid >> 6;
  const int wr = wave >> 1, wc = wave & 1;
  const size_t rb = (size_t)blockIdx.y * 128;
  const size_t cb = (size_t)blockIdx.x * 128;
  f32x4 acc[4][4];
#pragma unroll
  for (int i = 0; i < 4; ++i)
#pragma unroll
    for (int j = 0; j < 4; ++j) acc[i][j] = (f32x4){0.f, 0.f, 0.f, 0.f};

  for (int k0 = 0; k0 < K; k0 += 32) {
    __syncthreads();
#pragma unroll
    for (int c = 0; c < 2; ++c) {
      const int o = c * 4096 + wave * 1024 + lane * 16;
      const int r = o >> 6;
      const int col = (o >> 1) & 31;
      load_lds16(A + (rb + r) * K + k0 + col, As + (c * 4096 + wave * 1024) / 2);
      load_lds16(Bw + (cb + r) * K + k0 + col, Bs + (c * 4096 + wave * 1024) / 2);
    }
    __syncthreads();
    short8 a[4], b[4];
#pragma unroll
    for (int i = 0; i < 4; ++i) {
      a[i] = *(const short8*)(As + (wr * 64 + i * 16 + (lane & 15)) * 32 + (lane >> 4) * 8);
      b[i] = *(const short8*)(Bs + (wc * 64 + i * 16 + (lane & 15)) * 32 + (lane >> 4) * 8);
    }
#pragma unroll
    for (int i = 0; i < 4; ++i)
#pragma unroll
      for (int j = 0; j < 4; ++j)
        acc[i][j] = __builtin_amdgcn_mfma_f32_16x16x32_bf16(a[i], b[j], acc[i][j], 0, 0, 0);
  }
#pragma unroll
  for (int i = 0; i < 4; ++i) {
    const size_t r0 = rb + wr * 64 + i * 16 + ((lane >> 4) * 4);
#pragma unroll
    for (int j = 0; j < 4; ++j) {
      const size_t c0 = cb + wc * 64 + j * 16 + (lane & 15);
#pragma unroll
      for (int r = 0; r < 4; ++r) {
        float v = acc[i][j][r];
        if constexpr (sizeof(OutT) == 2) C[(r0 + r) * N + c0] = f2b(v);
        else                             C[(r0 + r) * N + c0] = v;
      }
    }
  }
}

// ---------------- causal GQA flash attention, 32x32 swapped-operand structure ----------------
// Block: 4 waves x 32 q-rows = 128 q-rows; q-tile pair (i, 15-i); KVBLK=64.
// Swapped QK^T: P^T = mfma(K, Q) -> lane owns q-row (col), holds half the kv per lane.
// Swapped PV:   O^T = mfma(V^T, P^T) -> lane owns q-row; softmax state per-lane scalar.
__global__ __launch_bounds__(256) void flash_attn(const ushort_t* __restrict__ q,
                                                  const ushort_t* __restrict__ k,
                                                  const ushort_t* __restrict__ vt,
                                                  ushort_t* __restrict__ out) {
  __shared__ ushort_t Ks[2][64 * 64];   // [kv][d], swizzled
  __shared__ ushort_t Vs[2][64 * 64];   // [d][kv], swizzled (from vt)
  const int pairIdx = blockIdx.x, h = blockIdx.y, b = blockIdx.z;
  const int g = h >> 2;                 // REP = 4
  const int tid = threadIdx.x, lane = tid & 63, wave = tid >> 6;
  const int l31 = lane & 31, hi = lane >> 5;

  // staging geometry (16B per thread per pass, 2 passes each for K and V)
  int srcRow[2], srcCol[2], ldsOff[2];
#pragma unroll
  for (int c = 0; c < 2; ++c) {
    const int o = c * 4096 + wave * 1024 + lane * 16;      // byte offset in 8KB buffer
    const int r = o >> 7;                                   // 128B rows
    srcRow[c] = r;
    srcCol[c] = ((o & 127) ^ ((r & 7) << 4)) >> 1;          // pre-swizzled source col
    ldsOff[c] = (c * 4096 + wave * 1024) / 2;
  }
  const ushort_t* kbase = k + (size_t)b * S_LEN * QKV_N + g * HD;
  const ushort_t* vbase = vt + (size_t)(b * NKV + g) * HD * S_LEN;

#pragma unroll 1
  for (int halfi = 0; halfi < 2; ++halfi) {
    const int qt = (halfi == 0) ? pairIdx : (15 - pairIdx);
    const int q0 = qt * 128;
    const int qwbase = q0 + wave * 32;        // first q-row of this wave
    const int qglob = qwbase + l31;           // this lane's q-row

    // Q fragments: lane holds Q[qglob][d = s*16 + hi*8 .. +7]
    short8 qf[4];
    {
      const ushort_t* qp = q + (size_t)(b * S_LEN + qglob) * QKV_N + h * HD + hi * 8;
#pragma unroll
      for (int s = 0; s < 4; ++s) qf[s] = *(const short8*)(qp + s * 16);
    }
    f32x16 oacc[2];
#pragma unroll
    for (int d = 0; d < 2; ++d)
#pragma unroll
      for (int r = 0; r < 16; ++r) oacc[d][r] = 0.f;
    float msc = -3e38f, lrow = 0.f;

    // prologue: stage tile 0 into buf 0
#pragma unroll
    for (int c = 0; c < 2; ++c) {
      load_lds16(kbase + (size_t)srcRow[c] * QKV_N + srcCol[c], &Ks[0][ldsOff[c]]);
      load_lds16(vbase + (size_t)srcRow[c] * S_LEN + srcCol[c], &Vs[0][ldsOff[c]]);
    }
    __syncthreads();

    int cur = 0;
    const int nt = 2 * (qt + 1);
    for (int t = 0; t < nt; ++t) {
      const int kv0 = t * 64;
      // stage next tile (overlaps with compute)
      if (t + 1 < nt) {
        const int nk = kv0 + 64;
#pragma unroll
        for (int c = 0; c < 2; ++c) {
          load_lds16(kbase + (size_t)(nk + srcRow[c]) * QKV_N + srcCol[c], &Ks[cur ^ 1][ldsOff[c]]);
          load_lds16(vbase + (size_t)srcRow[c] * S_LEN + nk + srcCol[c], &Vs[cur ^ 1][ldsOff[c]]);
        }
      }
      if (kv0 <= qwbase + 31) {           // wave-uniform causal activity guard
        // QK^T (swapped): pacc[j] = K-subtile-j . Q^T ; lane col = q-row
        f32x16 pacc[2];
#pragma unroll
        for (int j = 0; j < 2; ++j) {
          f32x16 z;
#pragma unroll
          for (int r = 0; r < 16; ++r) z[r] = 0.f;
#pragma unroll
          for (int s = 0; s < 4; ++s) {
            short8 kf = ld_swz(Ks[cur], j * 32 + l31, s * 16 + hi * 8);
            z = __builtin_amdgcn_mfma_f32_32x32x16_bf16(kf, qf[s], z, 0, 0, 0);
          }
          pacc[j] = z;
        }
        // causal mask (raw scores), only when the tile touches the diagonal
        if (kv0 + 63 > qwbase) {
#pragma unroll
          for (int j = 0; j < 2; ++j)
#pragma unroll
            for (int r = 0; r < 16; ++r) {
              const int kvabs = kv0 + j * 32 + (r & 3) + 8 * (r >> 2) + 4 * hi;
              pacc[j][r] = (kvabs <= qglob) ? pacc[j][r] : -1e30f;
            }
        }
        // in-register online softmax (row lives in lane + lane^32)
        float mraw = -3e38f;
#pragma unroll
        for (int j = 0; j < 2; ++j)
#pragma unroll
          for (int r = 0; r < 16; ++r) mraw = fmaxf(mraw, pacc[j][r]);
        mraw = fmaxf(mraw, __shfl_xor(mraw, 32));
        const float mscn = fmaxf(msc, mraw * SCL);
        const float sold = exp2f(msc - mscn);
        msc = mscn;
        float rs = 0.f;
        short8 pf[4];
#pragma unroll
        for (int j = 0; j < 2; ++j) {
          float pv[16];
#pragma unroll
          for (int r = 0; r < 16; ++r) {
            pv[r] = exp2f(pacc[j][r] * SCL - msc);
            rs += pv[r];
          }
          uint32_t w0 = cvtpk(pv[0], pv[1]),  w1 = cvtpk(pv[2], pv[3]);
          uint32_t w2 = cvtpk(pv[4], pv[5]),  w3 = cvtpk(pv[6], pv[7]);
          uint32_t w4 = cvtpk(pv[8], pv[9]),  w5 = cvtpk(pv[10], pv[11]);
          uint32_t w6 = cvtpk(pv[12], pv[13]), w7 = cvtpk(pv[14], pv[15]);
          pswap(w0, w2); pswap(w1, w3); pswap(w4, w6); pswap(w5, w7);
          pf[2 * j]     = mk8(w0, w1, w2, w3);   // kv 16*(2j)   .. +15
          pf[2 * j + 1] = mk8(w4, w5, w6, w7);   // kv 16*(2j+1) .. +15
        }
        rs += __shfl_xor(rs, 32);
        lrow = lrow * sold + rs;
        // rescale O and PV (swapped): oacc[dblk] += V^T-subtile . P^T
#pragma unroll
        for (int dblk = 0; dblk < 2; ++dblk) {
#pragma unroll
          for (int r = 0; r < 16; ++r) oacc[dblk][r] *= sold;
#pragma unroll
          for (int s = 0; s < 4; ++s) {
            short8 vf = ld_swz(Vs[cur], dblk * 32 + l31, s * 16 + hi * 8);
            oacc[dblk] = __builtin_amdgcn_mfma_f32_32x32x16_bf16(vf, pf[s], oacc[dblk], 0, 0, 0);
          }
        }
      }
      __syncthreads();      // staged loads drained; both buffers consistent
      cur ^= 1;
    }
    // epilogue: normalize, repack to bf16 rows via cvtpk+permlane, 16B stores
    const float inv = 1.f / lrow;
    ushort_t* op = out + (size_t)(b * S_LEN + qglob) * (NH * HD) + h * HD;
#pragma unroll
    for (int dblk = 0; dblk < 2; ++dblk) {
      float ov[16];
#pragma unroll
      for (int r = 0; r < 16; ++r) ov[r] = oacc[dblk][r] * inv;
      uint32_t w0 = cvtpk(ov[0], ov[1]),  w1 = cvtpk(ov[2], ov[3]);
      uint32_t w2 = cvtpk(ov[4], ov[5]),  w3 = cvtpk(ov[6], ov[7]);
      uint32_t w4 = cvtpk(ov[8], ov[9]),  w5 = cvtpk(ov[10], ov[11]);
      uint32_t w6 = cvtpk(ov[12], ov[13]), w7 = cvtpk(ov[14], ov[15]);
      pswap(w0, w2); pswap(w1, w3); pswap(w4, w6); pswap(w5, w7);
      uint4 stlo; stlo.x = w0; stlo.y = w1; stlo.z = w2; stlo.w = w3;
      uint4 sthi; sthi.x = w4; sthi.y = w5; sthi.z = w6; sthi.w = w7;
      *(uint4*)(op + dblk * 32 + hi * 8)      = stlo;   // d = dblk*32 +  0..15
      *(uint4*)(op + dblk * 32 + 16 + hi * 8) = sthi;   // d = dblk*32 + 16..31
    }
  }
}

extern "C" void kernel_launch(void* const* d_in, const int* in_sizes, int n_in,
                              void* d_out, int out_size, void* d_ws, size_t ws_size,
                              hipStream_t stream) {
  const float* x  = (const float*)d_in[0];
  const float* fc = (const float*)d_in[1];
  const float* fs = (const float*)d_in[2];
  const float* wq = (const float*)d_in[3];
  const float* wk = (const float*)d_in[4];
  const float* wv = (const float*)d_in[5];
  const float* wo = (const float*)d_in[6];
  float* out = (float*)d_out;
  ushort_t* ws = (ushort_t*)d_ws;

  const size_t n_x   = (size_t)B_SZ * S_LEN * D_DIM;
  const size_t n_wq  = (size_t)NH * HD * D_DIM;
  const size_t n_wk  = (size_t)NKV * HD * D_DIM;
  const size_t n_qkv = (size_t)B_SZ * S_LEN * QKV_N;
  const size_t n_q   = (size_t)B_SZ * S_LEN * NH * HD;
  const size_t n_k   = (size_t)B_SZ * S_LEN * NKV * HD;

  size_t off = 0;
  ushort_t* xb   = ws + off; off += n_x;
  ushort_t* wqb  = ws + off; off += n_wq;   // wq | wk | wv contiguous = (3072, 2048)
  ushort_t* wkb  = ws + off; off += n_wk;
  ushort_t* wvb  = ws + off; off += n_wk;
  ushort_t* wob  = ws + off; off += n_wq;
  ushort_t* qkvb = ws + off; off += n_qkv;  // (4096, 3072): q | k | v
  ushort_t* vtb  = ws + off; off += n_k;
  ushort_t* ab   = ws + off; off += n_q;
  (void)ws_size; (void)in_sizes; (void)n_in; (void)out_size;

  auto cvt = [&](const float* src, ushort_t* dst, size_t n) {
    int n8 = (int)(n / 8);
    cvt_bf16<<<dim3((n8 + 255) / 256), dim3(256), 0, stream>>>(src, dst, n8);
  };
  cvt(x, xb, n_x);
  cvt(wq, wqb, n_wq);
  cvt(wk, wkb, n_wk);
  cvt(wv, wvb, n_wk);
  cvt(wo, wob, n_wq);

  const int M = B_SZ * S_LEN;  // 4096
  gemm_bt<ushort_t><<<dim3(QKV_N / 128, M / 128), 256, 0, stream>>>(xb, wqb, qkvb, M, QKV_N, D_DIM);

  rope_kernel<NH, 5><<<dim3((M * NH * 8) / 256), 256, 0, stream>>>(qkvb, fc, fs, M * NH * 8);
  rope_kernel<NKV, 3><<<dim3((M * NKV * 8) / 256), 256, 0, stream>>>(qkvb + K_OFF, fc, fs, M * NKV * 8);

  transpose_v<<<dim3(S_LEN / 64, NKV, B_SZ), 256, 0, stream>>>(qkvb + V_OFF, vtb);

  flash_attn<<<dim3(8, NH, B_SZ), 256, 0, stream>>>(qkvb, qkvb + K_OFF, vtb, ab);

  gemm_bt<float><<<dim3(D_DIM / 128, M / 128), 256, 0, stream>>>(ab, wob, out, M, D_DIM, D_DIM);
}